// Round 7
// baseline (385.229 us; speedup 1.0000x reference)
//
#include <hip/hip_runtime.h>

#define EPSV 1e-5f
#define HP 130            // padded H/W
#define HW 16384          // 128*128

typedef unsigned int u32;
typedef unsigned short bfu;                                    // bf16 storage
typedef __bf16 bf16x8 __attribute__((ext_vector_type(8)));
typedef float  f32x4  __attribute__((ext_vector_type(4)));

__device__ __forceinline__ bfu f2bf(float f){
  u32 u = __builtin_bit_cast(u32, f);
  return (bfu)((u + 0x7FFFu + ((u >> 16) & 1u)) >> 16);        // RNE
}
__device__ __forceinline__ float bf2f(bfu h){
  return __builtin_bit_cast(float, ((u32)h) << 16);
}
__device__ __forceinline__ f32x4 mfma16(bf16x8 a, bf16x8 b, f32x4 c){
  return __builtin_amdgcn_mfma_f32_16x16x32_bf16(a, b, c, 0, 0, 0);
}
__device__ __forceinline__ bf16x8 ldsfrag(const bfu* p){
  return __builtin_bit_cast(bf16x8, *(const uint4*)p);
}

// ---------------- prep kernels ----------------

// zero only the halo borders of catT / w11T / out3T (interiors are fully written)
__global__ void k_zero_border(bfu* catT, bfu* w11T, bfu* out3T){
  int i = blockIdx.x*256 + threadIdx.x;      // 4*516 border cells
  if (i >= 4*516) return;
  int b = i/516, r = i - b*516;
  int hp, wpp;
  if (r < 130){ hp = 0; wpp = r; }
  else if (r < 260){ hp = 129; wpp = r - 130; }
  else { int r2 = r - 260; hp = 1 + (r2 >> 1); wpp = (r2 & 1)*129; }
  int pix = (b*HP + hp)*HP + wpp;
  uint4 z = {0,0,0,0};
  uint4* c4 = (uint4*)catT  + (size_t)pix*16;
  uint4* w4 = (uint4*)w11T  + (size_t)pix*8;
  uint4* o4 = (uint4*)out3T + (size_t)pix*8;
  #pragma unroll
  for (int k = 0; k < 16; ++k) c4[k] = z;
  #pragma unroll
  for (int k = 0; k < 8; ++k){ w4[k] = z; o4[k] = z; }
}

// weight reorders -> bf16.  A11[tap][och128][cin128]; A12[t][tap2][c64][j64]; A3[tap2][oc64][j64]
__global__ void k_prep_w(const float* __restrict__ w11w, const float* __restrict__ w21w,
                         const float* __restrict__ w12w, const float* __restrict__ w3w,
                         bfu* A11, bfu* A12, bfu* A3){
  const int total = 147456 + 331776 + 36864;
  for (int i = blockIdx.x*256 + threadIdx.x; i < total; i += gridDim.x*256){
    float v; bfu* dst;
    if (i < 147456){
      int tap = i >> 14, och = (i >> 7) & 127, cin = i & 127;
      v = (och < 64) ? w11w[(och*128 + cin)*9 + tap] : w21w[((och-64)*128 + cin)*9 + tap];
      dst = A11 + i;
    } else if (i < 147456 + 331776){
      int i2 = i - 147456;
      int g = i2 >> 12, t = g/9, tap2 = g%9;
      int c = (i2 >> 6) & 63, j = i2 & 63;
      v = w12w[((c*9 + t)*64 + j)*9 + tap2];
      dst = A12 + i2;
    } else {
      int i3 = i - (147456 + 331776);
      int tap2 = i3 >> 12, oc = (i3 >> 6) & 63, j = i3 & 63;
      v = w3w[(oc*64 + j)*9 + tap2];
      dst = A3 + i3;
    }
    *dst = f2bf(v);
  }
}

// catT interior: NHWC bf16 [b][130][130][128ch]; coalesced read via LDS transpose
__global__ void k_prep_cat(const float* __restrict__ inp, const float* __restrict__ wgt, bfu* catT){
  __shared__ bfu lds[128*136];
  int b = blockIdx.y, h = blockIdx.x;        // grid (128,4)
  int t = threadIdx.x;
  int w = t & 127, c0 = t >> 7;
  #pragma unroll 1
  for (int c = c0; c < 128; c += 2){
    const float* src = (c < 64) ? inp + ((b*64 + c)*128 + h)*128
                                : wgt + ((b*64 + (c-64))*128 + h)*128;
    lds[w*136 + c] = f2bf(src[w]);
  }
  __syncthreads();
  uint4* dst = (uint4*)catT;
  #pragma unroll
  for (int k = 0; k < 8; ++k){
    int idx = k*256 + t;
    int pix = idx >> 4, sub = idx & 15;
    uint4 v = *(const uint4*)&lds[pix*136 + sub*8];
    dst[(((b*HP + h+1)*HP) + (pix+1))*16 + sub] = v;
  }
}

// ---------------- k1: conv11 + conv21 (implicit GEMM, M=128, K=9*128) ----------------
__global__ __launch_bounds__(256) void k1_conv(
    const bfu* __restrict__ catT, const bfu* __restrict__ A11,
    const float* __restrict__ b11, const float* __restrict__ b21,
    bfu* __restrict__ w11T, float* __restrict__ poolP){
  __shared__ bfu lds[24480];
  int tid = threadIdx.x;
  int b = blockIdx.y, tile = blockIdx.x;     // 0..127
  int h0 = (tile >> 3)*8, w0 = (tile & 7)*16;

  const uint4* catT4 = (const uint4*)catT;
  for (int s = tid; s < 180*17; s += 256){
    int cell = s/17, sub = s%17;
    if (sub < 16){
      int th = cell/18, tw = cell%18;
      uint4 v = catT4[(((b*HP + h0+th)*HP) + (w0+tw))*16 + sub];
      *(uint4*)&lds[cell*136 + sub*8] = v;
    }
  }
  __syncthreads();

  int wid = tid >> 6, l = tid & 63, lg = l >> 4, pc = l & 15;
  int wm = wid >> 1, wn = wid & 1;
  f32x4 acc[4][4];
  #pragma unroll
  for (int i = 0; i < 4; ++i)
    #pragma unroll
    for (int j = 0; j < 4; ++j) acc[i][j] = f32x4{0.f,0.f,0.f,0.f};

  const uint4* A4 = (const uint4*)A11;
  #pragma unroll 3
  for (int tap = 0; tap < 9; ++tap){
    int kh = tap/3, kw = tap%3;
    #pragma unroll
    for (int jc = 0; jc < 4; ++jc){
      bf16x8 a[4], bb[4];
      #pragma unroll
      for (int fm = 0; fm < 4; ++fm){
        int row = wm*64 + fm*16 + pc;
        a[fm] = __builtin_bit_cast(bf16x8, A4[(tap*128 + row)*16 + jc*4 + lg]);
      }
      #pragma unroll
      for (int fn = 0; fn < 4; ++fn){
        int cell = (wn*4 + fn + kh)*18 + (pc + kw);
        bb[fn] = ldsfrag(&lds[cell*136 + jc*32 + lg*8]);
      }
      #pragma unroll
      for (int fm = 0; fm < 4; ++fm)
        #pragma unroll
        for (int fn = 0; fn < 4; ++fn)
          acc[fm][fn] = mfma16(a[fm], bb[fn], acc[fm][fn]);
    }
  }
  __syncthreads();

  if (wm == 0){
    #pragma unroll
    for (int fm = 0; fm < 4; ++fm)
      #pragma unroll
      for (int r = 0; r < 4; ++r){
        int och = fm*16 + lg*4 + r;
        float bias = b11[och];
        #pragma unroll
        for (int fn = 0; fn < 4; ++fn){
          float v = acc[fm][fn][r] + bias;
          v = v > 0.f ? v : 0.f;
          int px = wn*64 + fn*16 + pc;
          lds[px*72 + och] = f2bf(v);
        }
      }
  } else {
    float* statsF = (float*)&lds[20000];
    #pragma unroll
    for (int fm = 0; fm < 4; ++fm)
      #pragma unroll
      for (int r = 0; r < 4; ++r){
        int cw = fm*16 + lg*4 + r;
        float bias = b21[cw];
        float s = 0.f;
        #pragma unroll
        for (int fn = 0; fn < 4; ++fn){
          float v = acc[fm][fn][r] + bias;
          s += (v > 0.f ? v : 0.f);
        }
        s += __shfl_xor(s,1); s += __shfl_xor(s,2); s += __shfl_xor(s,4); s += __shfl_xor(s,8);
        if (pc == 0) statsF[wn*64 + cw] = s;
      }
  }
  __syncthreads();

  if (wid < 2){
    int px = tid;
    int h = h0 + (px >> 4), w = w0 + (px & 15);
    uint4* dst = (uint4*)w11T + (((b*HP + h+1)*HP) + (w+1))*8;
    const uint4* srcT = (const uint4*)&lds[px*72];
    #pragma unroll
    for (int k = 0; k < 8; ++k) dst[k] = srcT[k];
  }
  if (tid < 64){
    float* statsF = (float*)&lds[20000];
    poolP[(b*128 + tile)*64 + tid] = statsF[tid] + statsF[64 + tid];
  }
}

// ---------------- k2: pooled mean + w22 GEMV (bf16 output) ----------------
__global__ void k2a_pool(const float* __restrict__ poolP, float* pooled){
  int t = threadIdx.x;
  int b = t >> 6, c = t & 63;
  float s = 0.f;
  for (int tile = 0; tile < 128; ++tile) s += poolP[(b*128 + tile)*64 + c];
  pooled[t] = s * (1.f/16384.f);
}

__global__ void k2b_w22(const float* __restrict__ pooled, const float* __restrict__ W22,
                        const float* __restrict__ b22, bfu* __restrict__ w22bf){
  __shared__ float pl[64];
  int b = blockIdx.x >> 4, og = blockIdx.x & 15;
  if (threadIdx.x < 64) pl[threadIdx.x] = pooled[b*64 + threadIdx.x];
  __syncthreads();
  int o = og*256 + threadIdx.x;
  float acc = b22[o];
  #pragma unroll 4
  for (int c = 0; c < 64; ++c) acc += pl[c]*W22[o*64 + c];
  w22bf[b*4096 + o] = f2bf(acc);
}

// ---------------- k3: fused conv12 + local_conv + BN1 stats ----------------
// r6 restructure: 256 threads (4 waves), 8x16 px tile, grid (128,4)=512 blocks.
// Each wave: fm=4 (all 64 ch) x fn=2 (2 pixel rows), full 9-tap loop.
// y[4][2]+oacc[4][2] = 64 VGPR accum -> natural allocation fits w/o spill
// (r4-r6 lesson: 768-thr block ALWAYS spilled to 84 VGPR; attributes ignored.
//  TLP now from 2-4 co-resident BLOCKS per CU, which the allocator can't defeat.)
__global__ __launch_bounds__(256) void k3_fused(
    const bfu* __restrict__ w11T, const bfu* __restrict__ catT,
    const bfu* __restrict__ A12, const float* __restrict__ b12,
    float* __restrict__ out1, float* __restrict__ st1){
  __shared__ bfu ldsW[180*64];               // 23,040 B, swizzled (10x18 cells)
  __shared__ float b12f[576];                //  2,304 B
  __shared__ float wp[512];                  //  2,048 B
  int tid = threadIdx.x;
  int b = blockIdx.y, tile = blockIdx.x;     // 0..127
  int h0 = (tile >> 3)*8, w0 = (tile & 7)*16;

  const uint4* w11T4 = (const uint4*)w11T;
  for (int s = tid; s < 180*8; s += 256){
    int cell = s >> 3, sub = s & 7;
    int th = cell/18, tw = cell - th*18;
    uint4 v = w11T4[(((b*HP + h0+th)*HP) + (w0+tw))*8 + sub];
    *(uint4*)&ldsW[cell*64 + ((sub*8) ^ ((cell&7)<<3))] = v;
  }
  for (int i = tid; i < 576; i += 256) b12f[i] = b12[i];
  __syncthreads();

  int wid = tid >> 6, l = tid & 63, lg = l >> 4, pc = l & 15;
  int w2 = wid*2;
  const uint4* A4 = (const uint4*)A12;
  f32x4 oacc[4][2];
  #pragma unroll
  for (int i = 0; i < 4; ++i){ oacc[i][0] = f32x4{0.f,0.f,0.f,0.f}; oacc[i][1] = f32x4{0.f,0.f,0.f,0.f}; }

  #pragma unroll 1
  for (int tt = 0; tt < 9; ++tt){
    f32x4 y[4][2];
    #pragma unroll
    for (int i = 0; i < 4; ++i){ y[i][0] = f32x4{0.f,0.f,0.f,0.f}; y[i][1] = f32x4{0.f,0.f,0.f,0.f}; }

    #pragma unroll 3
    for (int tap2 = 0; tap2 < 9; ++tap2){
      int s = tt*9 + tap2;
      int kh = tap2/3, kw = tap2 - kh*3;
      #pragma unroll
      for (int jc = 0; jc < 2; ++jc){
        bf16x8 a[4], bb[2];
        #pragma unroll
        for (int fm = 0; fm < 4; ++fm)
          a[fm] = __builtin_bit_cast(bf16x8, A4[s*512 + (fm*16 + pc)*8 + jc*4 + lg]);
        #pragma unroll
        for (int fn = 0; fn < 2; ++fn){
          int cell = (w2 + fn + kh)*18 + (pc + kw);
          bb[fn] = ldsfrag(&ldsW[cell*64 + ((jc*32 + lg*8) ^ ((cell&7)<<3))]);
        }
        #pragma unroll
        for (int fm = 0; fm < 4; ++fm)
          #pragma unroll
          for (int fn = 0; fn < 2; ++fn)
            y[fm][fn] = mfma16(a[fm], bb[fn], y[fm][fn]);
      }
    }

    int dh = tt/3, dw = tt - dh*3;
    #pragma unroll
    for (int fn = 0; fn < 2; ++fn){
      const bfu* base = catT + ((size_t)((b*HP + h0 + w2 + fn + dh)*HP) + (w0 + pc + dw))*128 + lg*4;
      #pragma unroll
      for (int fm = 0; fm < 4; ++fm){
        ushort4 iv = *(const ushort4*)(base + fm*16);
        float i0 = bf2f(iv.x), i1 = bf2f(iv.y), i2 = bf2f(iv.z), i3 = bf2f(iv.w);
        int c = fm*16 + lg*4;
        oacc[fm][fn][0] += i0 * (y[fm][fn][0] + b12f[(c+0)*9 + tt]);
        oacc[fm][fn][1] += i1 * (y[fm][fn][1] + b12f[(c+1)*9 + tt]);
        oacc[fm][fn][2] += i2 * (y[fm][fn][2] + b12f[(c+2)*9 + tt]);
        oacc[fm][fn][3] += i3 * (y[fm][fn][3] + b12f[(c+3)*9 + tt]);
      }
    }
  }

  #pragma unroll
  for (int fm = 0; fm < 4; ++fm)
    #pragma unroll
    for (int r = 0; r < 4; ++r){
      int c = fm*16 + lg*4 + r;
      float s = 0.f, ss = 0.f;
      #pragma unroll
      for (int fn = 0; fn < 2; ++fn){
        float v = oacc[fm][fn][r];
        out1[((b*64 + c)*128 + h0 + w2 + fn)*128 + (w0 + pc)] = v;
        s += v; ss += v*v;
      }
      s += __shfl_xor(s,1); s += __shfl_xor(s,2); s += __shfl_xor(s,4); s += __shfl_xor(s,8);
      ss += __shfl_xor(ss,1); ss += __shfl_xor(ss,2); ss += __shfl_xor(ss,4); ss += __shfl_xor(ss,8);
      if (pc == 0){ wp[(wid*64 + c)*2] = s; wp[(wid*64 + c)*2 + 1] = ss; }
    }
  __syncthreads();
  if (tid < 64){
    float s = 0.f, ss = 0.f;
    #pragma unroll
    for (int w = 0; w < 4; ++w){ s += wp[(w*64 + tid)*2]; ss += wp[(w*64 + tid)*2 + 1]; }
    int blin = b*128 + tile;
    st1[(blin*64 + tid)*2] = s; st1[(blin*64 + tid)*2 + 1] = ss;
  }
}

// ---------------- BN stat reduce (coalesced, 256 threads) ----------------
__global__ void k_bnstat(const float* __restrict__ st, int nblk, float n,
                         const float* __restrict__ g, const float* __restrict__ bb, float* bn){
  __shared__ float red[512];
  int tid = threadIdx.x;
  int c = tid & 63, kk = tid >> 6;           // 4 k-groups
  float s = 0.f, ss = 0.f;
  for (int k = kk; k < nblk; k += 4){
    float2 v = *(const float2*)&st[(k*64 + c)*2];
    s += v.x; ss += v.y;
  }
  red[tid*2] = s; red[tid*2 + 1] = ss;
  __syncthreads();
  if (tid < 64){
    #pragma unroll
    for (int q = 1; q < 4; ++q){ s += red[(q*64 + tid)*2]; ss += red[(q*64 + tid)*2 + 1]; }
    float mean = s/n, var = ss/n - mean*mean;
    float a = g[tid]*rsqrtf(var + EPSV);
    bn[tid*2] = a; bn[tid*2 + 1] = bb[tid] - mean*a;
  }
}

// ---------------- k4: einsum as MFMA GEMM (64x256 tile, K=64) + BN2 stats ----------------
__global__ __launch_bounds__(256) void k4_einsum(
    const float* __restrict__ out1, const bfu* __restrict__ w22bf,
    const float* __restrict__ bn1, float* __restrict__ out2, float* __restrict__ st2){
  __shared__ bfu ldsX[256*72];               // [px][j], 144B rows
  __shared__ float a1[64], be1[64];
  __shared__ float wp[512];
  int tid = threadIdx.x;
  int b = blockIdx.y, chunk = blockIdx.x;    // 64 chunks of 256 px
  if (tid < 64){ a1[tid] = bn1[tid*2]; be1[tid] = bn1[tid*2 + 1]; }
  __syncthreads();
  int p0 = chunk*256;

  {
    int px = tid;
    const float* src = out1 + (size_t)(b*64)*HW + p0 + px;
    #pragma unroll 1
    for (int j0 = 0; j0 < 64; j0 += 4){
      float x0 = src[(j0+0)*HW]; x0 = a1[j0+0]*x0 + be1[j0+0]; x0 = x0 > 0.f ? x0 : 0.f;
      float x1 = src[(j0+1)*HW]; x1 = a1[j0+1]*x1 + be1[j0+1]; x1 = x1 > 0.f ? x1 : 0.f;
      float x2 = src[(j0+2)*HW]; x2 = a1[j0+2]*x2 + be1[j0+2]; x2 = x2 > 0.f ? x2 : 0.f;
      float x3 = src[(j0+3)*HW]; x3 = a1[j0+3]*x3 + be1[j0+3]; x3 = x3 > 0.f ? x3 : 0.f;
      ushort4 pk; pk.x = f2bf(x0); pk.y = f2bf(x1); pk.z = f2bf(x2); pk.w = f2bf(x3);
      *(ushort4*)&ldsX[px*72 + j0] = pk;
    }
  }
  __syncthreads();

  int wid = tid >> 6, l = tid & 63, lg = l >> 4, pc = l & 15;
  const uint4* W4 = (const uint4*)w22bf;
  f32x4 acc[4][4];
  #pragma unroll
  for (int i = 0; i < 4; ++i)
    #pragma unroll
    for (int j = 0; j < 4; ++j) acc[i][j] = f32x4{0.f,0.f,0.f,0.f};

  #pragma unroll
  for (int jc = 0; jc < 2; ++jc){
    bf16x8 a[4], bb[4];
    #pragma unroll
    for (int fm = 0; fm < 4; ++fm)
      a[fm] = __builtin_bit_cast(bf16x8, W4[b*512 + (fm*16 + pc)*8 + jc*4 + lg]);
    #pragma unroll
    for (int fn = 0; fn < 4; ++fn)
      bb[fn] = ldsfrag(&ldsX[(wid*64 + fn*16 + pc)*72 + jc*32 + lg*8]);
    #pragma unroll
    for (int fm = 0; fm < 4; ++fm)
      #pragma unroll
      for (int fn = 0; fn < 4; ++fn)
        acc[fm][fn] = mfma16(a[fm], bb[fn], acc[fm][fn]);
  }

  #pragma unroll
  for (int fm = 0; fm < 4; ++fm)
    #pragma unroll
    for (int r = 0; r < 4; ++r){
      int i = fm*16 + lg*4 + r;
      float s = 0.f, ss = 0.f;
      #pragma unroll
      for (int fn = 0; fn < 4; ++fn){
        int px = wid*64 + fn*16 + pc;
        float v = acc[fm][fn][r];
        out2[(b*64 + i)*HW + p0 + px] = v;
        s += v; ss += v*v;
      }
      s += __shfl_xor(s,1); s += __shfl_xor(s,2); s += __shfl_xor(s,4); s += __shfl_xor(s,8);
      ss += __shfl_xor(ss,1); ss += __shfl_xor(ss,2); ss += __shfl_xor(ss,4); ss += __shfl_xor(ss,8);
      if (pc == 0){ wp[(wid*64 + i)*2] = s; wp[(wid*64 + i)*2 + 1] = ss; }
    }
  __syncthreads();
  if (tid < 64){
    float s = 0.f, ss = 0.f;
    #pragma unroll
    for (int w = 0; w < 4; ++w){ s += wp[(w*64 + tid)*2]; ss += wp[(w*64 + tid)*2 + 1]; }
    int blin = b*64 + chunk;
    st2[(blin*64 + tid)*2] = s; st2[(blin*64 + tid)*2 + 1] = ss;
  }
}

// ---------------- k4c: out3T = relu(bn2(out2)) NHWC bf16, coalesced via LDS transpose ----------------
__global__ void k4c_out3(const float* __restrict__ out2, const float* __restrict__ bn2, bfu* out3T){
  __shared__ bfu lds[128*72];
  int b = blockIdx.y, h = blockIdx.x;        // grid (128,4)
  int t = threadIdx.x;
  int px = t & 127, ch = (t >> 7)*32;
  #pragma unroll 1
  for (int cc = 0; cc < 32; cc += 4){
    int c = ch + cc;
    float x0 = out2[((b*64 + c+0) << 14) + (h << 7) + px];
    float x1 = out2[((b*64 + c+1) << 14) + (h << 7) + px];
    float x2 = out2[((b*64 + c+2) << 14) + (h << 7) + px];
    float x3 = out2[((b*64 + c+3) << 14) + (h << 7) + px];
    x0 = bn2[(c+0)*2]*x0 + bn2[(c+0)*2+1]; x0 = x0 > 0.f ? x0 : 0.f;
    x1 = bn2[(c+1)*2]*x1 + bn2[(c+1)*2+1]; x1 = x1 > 0.f ? x1 : 0.f;
    x2 = bn2[(c+2)*2]*x2 + bn2[(c+2)*2+1]; x2 = x2 > 0.f ? x2 : 0.f;
    x3 = bn2[(c+3)*2]*x3 + bn2[(c+3)*2+1]; x3 = x3 > 0.f ? x3 : 0.f;
    ushort4 pk; pk.x = f2bf(x0); pk.y = f2bf(x1); pk.z = f2bf(x2); pk.w = f2bf(x3);
    *(ushort4*)&lds[px*72 + c] = pk;
  }
  __syncthreads();
  uint4* dst = (uint4*)out3T;
  #pragma unroll
  for (int k = 0; k < 4; ++k){
    int idx = k*256 + t;                     // 0..1023
    int pix = idx >> 3, sub = idx & 7;
    uint4 v = *(const uint4*)&lds[pix*72 + sub*8];
    dst[((size_t)(b*HP + h+1)*HP + (pix+1))*8 + sub] = v;
  }
}

// ---------------- k5: conv3 (implicit GEMM M=64,K=576), 512 blocks + BN3 stats ----------------
__global__ __launch_bounds__(256) void k5_conv3(
    const bfu* __restrict__ out3T, const bfu* __restrict__ A3,
    float* __restrict__ outc, float* __restrict__ st3){
  __shared__ bfu lds[180*72];                // 10x18 cells, 25,920 B
  __shared__ float wp[512];
  int tid = threadIdx.x;
  int b = blockIdx.y, tile = blockIdx.x;     // 0..127
  int h0 = (tile >> 3)*8, w0 = (tile & 7)*16;
  const uint4* src4 = (const uint4*)out3T;
  for (int s = tid; s < 180*8; s += 256){
    int cell = s >> 3, sub = s & 7;
    int th = cell/18, tw = cell - th*18;
    *(uint4*)&lds[cell*72 + sub*8] = src4[(((b*HP + h0+th)*HP) + (w0+tw))*8 + sub];
  }
  __syncthreads();

  int wid = tid >> 6, l = tid & 63, lg = l >> 4, pc = l & 15;
  f32x4 acc[4][2];
  #pragma unroll
  for (int i = 0; i < 4; ++i){ acc[i][0] = f32x4{0.f,0.f,0.f,0.f}; acc[i][1] = f32x4{0.f,0.f,0.f,0.f}; }
  const uint4* A4 = (const uint4*)A3;
  #pragma unroll 3
  for (int tap2 = 0; tap2 < 9; ++tap2){
    int kh = tap2/3, kw = tap2 - kh*3;
    #pragma unroll
    for (int jc = 0; jc < 2; ++jc){
      bf16x8 a[4], bb[2];
      #pragma unroll
      for (int fm = 0; fm < 4; ++fm)
        a[fm] = __builtin_bit_cast(bf16x8, A4[tap2*512 + (fm*16 + pc)*8 + jc*4 + lg]);
      #pragma unroll
      for (int fn = 0; fn < 2; ++fn){
        int cell = (wid*2 + fn + kh)*18 + (pc + kw);
        bb[fn] = ldsfrag(&lds[cell*72 + jc*32 + lg*8]);
      }
      #pragma unroll
      for (int fm = 0; fm < 4; ++fm)
        #pragma unroll
        for (int fn = 0; fn < 2; ++fn)
          acc[fm][fn] = mfma16(a[fm], bb[fn], acc[fm][fn]);
    }
  }
  #pragma unroll
  for (int fm = 0; fm < 4; ++fm)
    #pragma unroll
    for (int r = 0; r < 4; ++r){
      int c = fm*16 + lg*4 + r;
      float s = 0.f, ss = 0.f;
      #pragma unroll
      for (int fn = 0; fn < 2; ++fn){
        int pr = wid*2 + fn;
        float v = acc[fm][fn][r];
        outc[((b*64 + c)*128 + h0 + pr)*128 + (w0 + pc)] = v;
        s += v; ss += v*v;
      }
      s += __shfl_xor(s,1); s += __shfl_xor(s,2); s += __shfl_xor(s,4); s += __shfl_xor(s,8);
      ss += __shfl_xor(ss,1); ss += __shfl_xor(ss,2); ss += __shfl_xor(ss,4); ss += __shfl_xor(ss,8);
      if (pc == 0){ wp[(wid*64 + c)*2] = s; wp[(wid*64 + c)*2 + 1] = ss; }
    }
  __syncthreads();
  if (tid < 64){
    float s = 0.f, ss = 0.f;
    #pragma unroll
    for (int w = 0; w < 4; ++w){ s += wp[(w*64 + tid)*2]; ss += wp[(w*64 + tid)*2 + 1]; }
    int blin = b*128 + tile;
    st3[(blin*64 + tid)*2] = s; st3[(blin*64 + tid)*2 + 1] = ss;
  }
}

// ---------------- k6: final relu(bn3(conv3_pre)) in place, float4 ----------------
__global__ void k6_final(float4* __restrict__ out, const float* __restrict__ bn3){
  const int total4 = 4*64*HW/4;              // 1,048,576
  for (int i = blockIdx.x*256 + threadIdx.x; i < total4; i += gridDim.x*256){
    int c = (i >> 12) & 63;
    float a = bn3[c*2], be = bn3[c*2 + 1];
    float4 x = out[i];
    x.x = a*x.x + be; x.x = x.x > 0.f ? x.x : 0.f;
    x.y = a*x.y + be; x.y = x.y > 0.f ? x.y : 0.f;
    x.z = a*x.z + be; x.z = x.z > 0.f ? x.z : 0.f;
    x.w = a*x.w + be; x.w = x.w > 0.f ? x.w : 0.f;
    out[i] = x;
  }
}

extern "C" void kernel_launch(void* const* d_in, const int* in_sizes, int n_in,
                              void* d_out, int out_size, void* d_ws, size_t ws_size,
                              hipStream_t stream){
  const float* inp  = (const float*)d_in[0];
  const float* wgt  = (const float*)d_in[1];
  const float* w11w = (const float*)d_in[2];
  const float* b11  = (const float*)d_in[3];
  const float* w12w = (const float*)d_in[4];
  const float* b12  = (const float*)d_in[5];
  const float* w21w = (const float*)d_in[6];
  const float* b21  = (const float*)d_in[7];
  const float* W22  = (const float*)d_in[8];
  const float* b22  = (const float*)d_in[9];
  const float* lg   = (const float*)d_in[10];
  const float* lb   = (const float*)d_in[11];
  const float* brg  = (const float*)d_in[12];
  const float* brb  = (const float*)d_in[13];
  const float* w3w  = (const float*)d_in[14];
  const float* c3g  = (const float*)d_in[15];
  const float* c3b  = (const float*)d_in[16];

  if (ws_size < 53200000) return;

  char* ws = (char*)d_ws;
  bfu*   catT  = (bfu*)(ws);                     // 17,305,600
  bfu*   w11T  = (bfu*)(ws + 17305600);          //  8,652,800
  bfu*   out3T = (bfu*)(ws + 25958400);          //  8,652,800
  bfu*   A11   = (bfu*)(ws + 34611200);          //    294,912
  bfu*   A12   = (bfu*)(ws + 34906112);          //    663,552
  bfu*   A3    = (bfu*)(ws + 35569664);          //     73,728
  float* out1  = (float*)(ws + 35643392);        // 16,777,216
  float* poolP = (float*)(ws + 52420608);        //    131,072
  float* pooled= (float*)(ws + 52551680);        //      1,024
  bfu*   w22bf = (bfu*)(ws + 52552704);          //     32,768
  float* st13  = (float*)(ws + 52585472);        //    262,144 (st1 then st3 — disjoint in time)
  float* bn1   = (float*)(ws + 52847616);        //        512
  float* st2   = (float*)(ws + 52848128);        //    131,072
  float* bn2   = (float*)(ws + 52979200);        //        512
  float* bn3   = (float*)(ws + 52979712);        //        512
  float* outF  = (float*)d_out;

  k_zero_border<<<dim3(9),  dim3(256), 0, stream>>>(catT, w11T, out3T);
  k_prep_w  <<<dim3(512),  dim3(256), 0, stream>>>(w11w, w21w, w12w, w3w, A11, A12, A3);
  k_prep_cat<<<dim3(128,4),dim3(256), 0, stream>>>(inp, wgt, catT);
  k1_conv   <<<dim3(128,4),dim3(256), 0, stream>>>(catT, A11, b11, b21, w11T, poolP);
  k2a_pool  <<<dim3(1),    dim3(256), 0, stream>>>(poolP, pooled);
  k2b_w22   <<<dim3(64),   dim3(256), 0, stream>>>(pooled, W22, b22, w22bf);
  k3_fused  <<<dim3(128,4),dim3(256), 0, stream>>>(w11T, catT, A12, b12, out1, st13);
  k_bnstat  <<<dim3(1),    dim3(256), 0, stream>>>(st13, 512, 65536.f, lg, lb, bn1);
  k4_einsum <<<dim3(64,4), dim3(256), 0, stream>>>(out1, w22bf, bn1, outF, st2);
  k_bnstat  <<<dim3(1),    dim3(256), 0, stream>>>(st2, 256, 65536.f, brg, brb, bn2);
  k4c_out3  <<<dim3(128,4),dim3(256), 0, stream>>>(outF, bn2, out3T);
  k5_conv3  <<<dim3(128,4),dim3(256), 0, stream>>>(out3T, A3, outF, st13);
  k_bnstat  <<<dim3(1),    dim3(256), 0, stream>>>(st13, 512, 65536.f, c3g, c3b, bn3);
  k6_final  <<<dim3(1024), dim3(256), 0, stream>>>((float4*)outF, bn3);
}

// Round 8
// 273.158 us; speedup vs baseline: 1.4103x; 1.4103x over previous
//
#include <hip/hip_runtime.h>

#define EPSV 1e-5f
#define HP 130            // padded H/W
#define HW 16384          // 128*128

typedef unsigned int u32;
typedef unsigned short bfu;                                    // bf16 storage
typedef __bf16 bf16x8 __attribute__((ext_vector_type(8)));
typedef float  f32x4  __attribute__((ext_vector_type(4)));

__device__ __forceinline__ bfu f2bf(float f){
  u32 u = __builtin_bit_cast(u32, f);
  return (bfu)((u + 0x7FFFu + ((u >> 16) & 1u)) >> 16);        // RNE
}
__device__ __forceinline__ float bf2f(bfu h){
  return __builtin_bit_cast(float, ((u32)h) << 16);
}
__device__ __forceinline__ f32x4 mfma16(bf16x8 a, bf16x8 b, f32x4 c){
  return __builtin_amdgcn_mfma_f32_16x16x32_bf16(a, b, c, 0, 0, 0);
}
__device__ __forceinline__ bf16x8 ldsfrag(const bfu* p){
  return __builtin_bit_cast(bf16x8, *(const uint4*)p);
}

// ---------------- prep kernels ----------------

// zero only the halo borders of catT / w11T / out3T (interiors are fully written)
__global__ void k_zero_border(bfu* catT, bfu* w11T, bfu* out3T){
  int i = blockIdx.x*256 + threadIdx.x;      // 4*516 border cells
  if (i >= 4*516) return;
  int b = i/516, r = i - b*516;
  int hp, wpp;
  if (r < 130){ hp = 0; wpp = r; }
  else if (r < 260){ hp = 129; wpp = r - 130; }
  else { int r2 = r - 260; hp = 1 + (r2 >> 1); wpp = (r2 & 1)*129; }
  int pix = (b*HP + hp)*HP + wpp;
  uint4 z = {0,0,0,0};
  uint4* c4 = (uint4*)catT  + (size_t)pix*16;
  uint4* w4 = (uint4*)w11T  + (size_t)pix*8;
  uint4* o4 = (uint4*)out3T + (size_t)pix*8;
  #pragma unroll
  for (int k = 0; k < 16; ++k) c4[k] = z;
  #pragma unroll
  for (int k = 0; k < 8; ++k){ w4[k] = z; o4[k] = z; }
}

// weight reorders -> bf16.  A11[tap][och128][cin128]; A12[t][tap2][c64][j64]; A3[tap2][oc64][j64]
__global__ void k_prep_w(const float* __restrict__ w11w, const float* __restrict__ w21w,
                         const float* __restrict__ w12w, const float* __restrict__ w3w,
                         bfu* A11, bfu* A12, bfu* A3){
  const int total = 147456 + 331776 + 36864;
  for (int i = blockIdx.x*256 + threadIdx.x; i < total; i += gridDim.x*256){
    float v; bfu* dst;
    if (i < 147456){
      int tap = i >> 14, och = (i >> 7) & 127, cin = i & 127;
      v = (och < 64) ? w11w[(och*128 + cin)*9 + tap] : w21w[((och-64)*128 + cin)*9 + tap];
      dst = A11 + i;
    } else if (i < 147456 + 331776){
      int i2 = i - 147456;
      int g = i2 >> 12, t = g/9, tap2 = g%9;
      int c = (i2 >> 6) & 63, j = i2 & 63;
      v = w12w[((c*9 + t)*64 + j)*9 + tap2];
      dst = A12 + i2;
    } else {
      int i3 = i - (147456 + 331776);
      int tap2 = i3 >> 12, oc = (i3 >> 6) & 63, j = i3 & 63;
      v = w3w[(oc*64 + j)*9 + tap2];
      dst = A3 + i3;
    }
    *dst = f2bf(v);
  }
}

// catT interior: NHWC bf16 [b][130][130][128ch]; coalesced read via LDS transpose
__global__ void k_prep_cat(const float* __restrict__ inp, const float* __restrict__ wgt, bfu* catT){
  __shared__ bfu lds[128*136];
  int b = blockIdx.y, h = blockIdx.x;        // grid (128,4)
  int t = threadIdx.x;
  int w = t & 127, c0 = t >> 7;
  #pragma unroll 1
  for (int c = c0; c < 128; c += 2){
    const float* src = (c < 64) ? inp + ((b*64 + c)*128 + h)*128
                                : wgt + ((b*64 + (c-64))*128 + h)*128;
    lds[w*136 + c] = f2bf(src[w]);
  }
  __syncthreads();
  uint4* dst = (uint4*)catT;
  #pragma unroll
  for (int k = 0; k < 8; ++k){
    int idx = k*256 + t;
    int pix = idx >> 4, sub = idx & 15;
    uint4 v = *(const uint4*)&lds[pix*136 + sub*8];
    dst[(((b*HP + h+1)*HP) + (pix+1))*16 + sub] = v;
  }
}

// ---------------- k1: conv11 + conv21 (implicit GEMM, M=128, K=9*128) ----------------
__global__ __launch_bounds__(256) void k1_conv(
    const bfu* __restrict__ catT, const bfu* __restrict__ A11,
    const float* __restrict__ b11, const float* __restrict__ b21,
    bfu* __restrict__ w11T, float* __restrict__ poolP){
  __shared__ bfu lds[24480];
  int tid = threadIdx.x;
  int b = blockIdx.y, tile = blockIdx.x;     // 0..127
  int h0 = (tile >> 3)*8, w0 = (tile & 7)*16;

  const uint4* catT4 = (const uint4*)catT;
  for (int s = tid; s < 180*17; s += 256){
    int cell = s/17, sub = s%17;
    if (sub < 16){
      int th = cell/18, tw = cell%18;
      uint4 v = catT4[(((b*HP + h0+th)*HP) + (w0+tw))*16 + sub];
      *(uint4*)&lds[cell*136 + sub*8] = v;
    }
  }
  __syncthreads();

  int wid = tid >> 6, l = tid & 63, lg = l >> 4, pc = l & 15;
  int wm = wid >> 1, wn = wid & 1;
  f32x4 acc[4][4];
  #pragma unroll
  for (int i = 0; i < 4; ++i)
    #pragma unroll
    for (int j = 0; j < 4; ++j) acc[i][j] = f32x4{0.f,0.f,0.f,0.f};

  const uint4* A4 = (const uint4*)A11;
  #pragma unroll 3
  for (int tap = 0; tap < 9; ++tap){
    int kh = tap/3, kw = tap%3;
    #pragma unroll
    for (int jc = 0; jc < 4; ++jc){
      bf16x8 a[4], bb[4];
      #pragma unroll
      for (int fm = 0; fm < 4; ++fm){
        int row = wm*64 + fm*16 + pc;
        a[fm] = __builtin_bit_cast(bf16x8, A4[(tap*128 + row)*16 + jc*4 + lg]);
      }
      #pragma unroll
      for (int fn = 0; fn < 4; ++fn){
        int cell = (wn*4 + fn + kh)*18 + (pc + kw);
        bb[fn] = ldsfrag(&lds[cell*136 + jc*32 + lg*8]);
      }
      #pragma unroll
      for (int fm = 0; fm < 4; ++fm)
        #pragma unroll
        for (int fn = 0; fn < 4; ++fn)
          acc[fm][fn] = mfma16(a[fm], bb[fn], acc[fm][fn]);
    }
  }
  __syncthreads();

  if (wm == 0){
    #pragma unroll
    for (int fm = 0; fm < 4; ++fm)
      #pragma unroll
      for (int r = 0; r < 4; ++r){
        int och = fm*16 + lg*4 + r;
        float bias = b11[och];
        #pragma unroll
        for (int fn = 0; fn < 4; ++fn){
          float v = acc[fm][fn][r] + bias;
          v = v > 0.f ? v : 0.f;
          int px = wn*64 + fn*16 + pc;
          lds[px*72 + och] = f2bf(v);
        }
      }
  } else {
    float* statsF = (float*)&lds[20000];
    #pragma unroll
    for (int fm = 0; fm < 4; ++fm)
      #pragma unroll
      for (int r = 0; r < 4; ++r){
        int cw = fm*16 + lg*4 + r;
        float bias = b21[cw];
        float s = 0.f;
        #pragma unroll
        for (int fn = 0; fn < 4; ++fn){
          float v = acc[fm][fn][r] + bias;
          s += (v > 0.f ? v : 0.f);
        }
        s += __shfl_xor(s,1); s += __shfl_xor(s,2); s += __shfl_xor(s,4); s += __shfl_xor(s,8);
        if (pc == 0) statsF[wn*64 + cw] = s;
      }
  }
  __syncthreads();

  if (wid < 2){
    int px = tid;
    int h = h0 + (px >> 4), w = w0 + (px & 15);
    uint4* dst = (uint4*)w11T + (((b*HP + h+1)*HP) + (w+1))*8;
    const uint4* srcT = (const uint4*)&lds[px*72];
    #pragma unroll
    for (int k = 0; k < 8; ++k) dst[k] = srcT[k];
  }
  if (tid < 64){
    float* statsF = (float*)&lds[20000];
    poolP[(b*128 + tile)*64 + tid] = statsF[tid] + statsF[64 + tid];
  }
}

// ---------------- k2: pooled mean + w22 GEMV (bf16 output) ----------------
__global__ void k2a_pool(const float* __restrict__ poolP, float* pooled){
  int t = threadIdx.x;
  int b = t >> 6, c = t & 63;
  float s = 0.f;
  for (int tile = 0; tile < 128; ++tile) s += poolP[(b*128 + tile)*64 + c];
  pooled[t] = s * (1.f/16384.f);
}

__global__ void k2b_w22(const float* __restrict__ pooled, const float* __restrict__ W22,
                        const float* __restrict__ b22, bfu* __restrict__ w22bf){
  __shared__ float pl[64];
  int b = blockIdx.x >> 4, og = blockIdx.x & 15;
  if (threadIdx.x < 64) pl[threadIdx.x] = pooled[b*64 + threadIdx.x];
  __syncthreads();
  int o = og*256 + threadIdx.x;
  float acc = b22[o];
  #pragma unroll 4
  for (int c = 0; c < 64; ++c) acc += pl[c]*W22[o*64 + c];
  w22bf[b*4096 + o] = f2bf(acc);
}

// ---------------- k3: fused conv12 + local_conv + BN1 stats ----------------
// r7 lesson: per-wave A12 reads from L2 are the bottleneck (1.3GB @ 12 B/cyc/CU,
// latency-bound). Fix: stage the per-tt A12 slice (9x64x64 bf16 = 73.7KB) into
// LDS once per block in FRAG-LINEAR layout (r2-verified mapping), so fragment
// reads are contiguous conflict-free ds_read_b128. L2 A-traffic: 1.3GB -> 170MB.
// 16x16 px tile, 4 waves fn=4, 18 barriers total. LDS 119.5KB -> 1 block/CU;
// bottleneck becomes CU-level LDS BW (~5.2MB @ 85B/cyc ~ 25us) overlapped w/ MFMA.
__global__ __launch_bounds__(256) void k3_fused(
    const bfu* __restrict__ w11T, const bfu* __restrict__ catT,
    const bfu* __restrict__ A12, const float* __restrict__ b12,
    float* __restrict__ out1, float* __restrict__ st1){
  __shared__ bfu ldsW[324*64];               // 41,472 B, swizzled (18x18 cells)
  __shared__ bfu ldsA[9*4096];               // 73,728 B, frag-linear per-tt slice
  __shared__ float b12f[576];                //  2,304 B
  __shared__ float wp[512];                  //  2,048 B
  int tid = threadIdx.x;
  int b = blockIdx.y, tile = blockIdx.x;     // 0..63
  int h0 = (tile >> 3)*16, w0 = (tile & 7)*16;

  const uint4* w11T4 = (const uint4*)w11T;
  for (int s = tid; s < 324*8; s += 256){
    int cell = s >> 3, sub = s & 7;
    int th = cell/18, tw = cell - th*18;
    uint4 v = w11T4[(((b*HP + h0+th)*HP) + (w0+tw))*8 + sub];
    *(uint4*)&ldsW[cell*64 + ((sub*8) ^ ((cell&7)<<3))] = v;
  }
  for (int i = tid; i < 576; i += 256) b12f[i] = b12[i];

  // A stage mapping (r2-verified): thread owns global uint4 pair g = 2*tid, 2*tid+1
  // of each 512-uint4 (tap2) sub-slice; frag-linear dst = ((fm*2+jc)*4+lg)*16+pc.
  const uint4* A4 = (const uint4*)A12;
  uint4* ldsA4 = (uint4*)ldsA;
  int fmT = tid >> 6, rT = (tid >> 2) & 15;
  int jcT = (tid & 3) >> 1, lg0 = (tid & 1)*2;
  int dstA = ((fmT*2 + jcT)*4 + lg0)*16 + rT;

  int wid = tid >> 6, l = tid & 63, lg = l >> 4, pc = l & 15;
  int w4 = wid*4;
  f32x4 oacc[4][4];
  #pragma unroll
  for (int i = 0; i < 4; ++i)
    #pragma unroll
    for (int j = 0; j < 4; ++j) oacc[i][j] = f32x4{0.f,0.f,0.f,0.f};

  #pragma unroll 1
  for (int tt = 0; tt < 9; ++tt){
    __syncthreads();                         // prev slice consumed (tt=0: ldsW ready)
    #pragma unroll
    for (int tap2 = 0; tap2 < 9; ++tap2){
      uint4 g0 = A4[(tt*9 + tap2)*512 + tid*2];
      uint4 g1 = A4[(tt*9 + tap2)*512 + tid*2 + 1];
      ldsA4[tap2*512 + dstA]      = g0;
      ldsA4[tap2*512 + dstA + 16] = g1;
    }
    __syncthreads();                         // slice ready

    f32x4 y[4][4];
    #pragma unroll
    for (int i = 0; i < 4; ++i)
      #pragma unroll
      for (int j = 0; j < 4; ++j) y[i][j] = f32x4{0.f,0.f,0.f,0.f};

    #pragma unroll 3
    for (int tap2 = 0; tap2 < 9; ++tap2){
      int kh = tap2/3, kw = tap2 - kh*3;
      #pragma unroll
      for (int jc = 0; jc < 2; ++jc){
        bf16x8 a[4], bb[4];
        #pragma unroll
        for (int fm = 0; fm < 4; ++fm)
          a[fm] = __builtin_bit_cast(bf16x8, ldsA4[tap2*512 + (fm*2 + jc)*64 + l]);
        #pragma unroll
        for (int fn = 0; fn < 4; ++fn){
          int cell = (w4 + fn + kh)*18 + (pc + kw);
          bb[fn] = ldsfrag(&ldsW[cell*64 + ((jc*32 + lg*8) ^ ((cell&7)<<3))]);
        }
        #pragma unroll
        for (int fm = 0; fm < 4; ++fm)
          #pragma unroll
          for (int fn = 0; fn < 4; ++fn)
            y[fm][fn] = mfma16(a[fm], bb[fn], y[fm][fn]);
      }
    }

    int dh = tt/3, dw = tt - dh*3;
    #pragma unroll
    for (int fn = 0; fn < 4; ++fn){
      const bfu* base = catT + ((size_t)((b*HP + h0 + w4 + fn + dh)*HP) + (w0 + pc + dw))*128 + lg*4;
      #pragma unroll
      for (int fm = 0; fm < 4; ++fm){
        ushort4 iv = *(const ushort4*)(base + fm*16);
        float i0 = bf2f(iv.x), i1 = bf2f(iv.y), i2 = bf2f(iv.z), i3 = bf2f(iv.w);
        int c = fm*16 + lg*4;
        oacc[fm][fn][0] += i0 * (y[fm][fn][0] + b12f[(c+0)*9 + tt]);
        oacc[fm][fn][1] += i1 * (y[fm][fn][1] + b12f[(c+1)*9 + tt]);
        oacc[fm][fn][2] += i2 * (y[fm][fn][2] + b12f[(c+2)*9 + tt]);
        oacc[fm][fn][3] += i3 * (y[fm][fn][3] + b12f[(c+3)*9 + tt]);
      }
    }
  }

  #pragma unroll
  for (int fm = 0; fm < 4; ++fm)
    #pragma unroll
    for (int r = 0; r < 4; ++r){
      int c = fm*16 + lg*4 + r;
      float s = 0.f, ss = 0.f;
      #pragma unroll
      for (int fn = 0; fn < 4; ++fn){
        float v = oacc[fm][fn][r];
        out1[((b*64 + c)*128 + h0 + w4 + fn)*128 + (w0 + pc)] = v;
        s += v; ss += v*v;
      }
      s += __shfl_xor(s,1); s += __shfl_xor(s,2); s += __shfl_xor(s,4); s += __shfl_xor(s,8);
      ss += __shfl_xor(ss,1); ss += __shfl_xor(ss,2); ss += __shfl_xor(ss,4); ss += __shfl_xor(ss,8);
      if (pc == 0){ wp[(wid*64 + c)*2] = s; wp[(wid*64 + c)*2 + 1] = ss; }
    }
  __syncthreads();
  if (tid < 64){
    float s = 0.f, ss = 0.f;
    #pragma unroll
    for (int w = 0; w < 4; ++w){ s += wp[(w*64 + tid)*2]; ss += wp[(w*64 + tid)*2 + 1]; }
    int blin = b*64 + tile;
    st1[(blin*64 + tid)*2] = s; st1[(blin*64 + tid)*2 + 1] = ss;
  }
}

// ---------------- BN stat reduce (coalesced, 256 threads) ----------------
__global__ void k_bnstat(const float* __restrict__ st, int nblk, float n,
                         const float* __restrict__ g, const float* __restrict__ bb, float* bn){
  __shared__ float red[512];
  int tid = threadIdx.x;
  int c = tid & 63, kk = tid >> 6;           // 4 k-groups
  float s = 0.f, ss = 0.f;
  for (int k = kk; k < nblk; k += 4){
    float2 v = *(const float2*)&st[(k*64 + c)*2];
    s += v.x; ss += v.y;
  }
  red[tid*2] = s; red[tid*2 + 1] = ss;
  __syncthreads();
  if (tid < 64){
    #pragma unroll
    for (int q = 1; q < 4; ++q){ s += red[(q*64 + tid)*2]; ss += red[(q*64 + tid)*2 + 1]; }
    float mean = s/n, var = ss/n - mean*mean;
    float a = g[tid]*rsqrtf(var + EPSV);
    bn[tid*2] = a; bn[tid*2 + 1] = bb[tid] - mean*a;
  }
}

// ---------------- k4: einsum as MFMA GEMM (64x256 tile, K=64) + BN2 stats ----------------
__global__ __launch_bounds__(256) void k4_einsum(
    const float* __restrict__ out1, const bfu* __restrict__ w22bf,
    const float* __restrict__ bn1, float* __restrict__ out2, float* __restrict__ st2){
  __shared__ bfu ldsX[256*72];               // [px][j], 144B rows
  __shared__ float a1[64], be1[64];
  __shared__ float wp[512];
  int tid = threadIdx.x;
  int b = blockIdx.y, chunk = blockIdx.x;    // 64 chunks of 256 px
  if (tid < 64){ a1[tid] = bn1[tid*2]; be1[tid] = bn1[tid*2 + 1]; }
  __syncthreads();
  int p0 = chunk*256;

  {
    int px = tid;
    const float* src = out1 + (size_t)(b*64)*HW + p0 + px;
    #pragma unroll 1
    for (int j0 = 0; j0 < 64; j0 += 4){
      float x0 = src[(j0+0)*HW]; x0 = a1[j0+0]*x0 + be1[j0+0]; x0 = x0 > 0.f ? x0 : 0.f;
      float x1 = src[(j0+1)*HW]; x1 = a1[j0+1]*x1 + be1[j0+1]; x1 = x1 > 0.f ? x1 : 0.f;
      float x2 = src[(j0+2)*HW]; x2 = a1[j0+2]*x2 + be1[j0+2]; x2 = x2 > 0.f ? x2 : 0.f;
      float x3 = src[(j0+3)*HW]; x3 = a1[j0+3]*x3 + be1[j0+3]; x3 = x3 > 0.f ? x3 : 0.f;
      ushort4 pk; pk.x = f2bf(x0); pk.y = f2bf(x1); pk.z = f2bf(x2); pk.w = f2bf(x3);
      *(ushort4*)&ldsX[px*72 + j0] = pk;
    }
  }
  __syncthreads();

  int wid = tid >> 6, l = tid & 63, lg = l >> 4, pc = l & 15;
  const uint4* W4 = (const uint4*)w22bf;
  f32x4 acc[4][4];
  #pragma unroll
  for (int i = 0; i < 4; ++i)
    #pragma unroll
    for (int j = 0; j < 4; ++j) acc[i][j] = f32x4{0.f,0.f,0.f,0.f};

  #pragma unroll
  for (int jc = 0; jc < 2; ++jc){
    bf16x8 a[4], bb[4];
    #pragma unroll
    for (int fm = 0; fm < 4; ++fm)
      a[fm] = __builtin_bit_cast(bf16x8, W4[b*512 + (fm*16 + pc)*8 + jc*4 + lg]);
    #pragma unroll
    for (int fn = 0; fn < 4; ++fn)
      bb[fn] = ldsfrag(&ldsX[(wid*64 + fn*16 + pc)*72 + jc*32 + lg*8]);
    #pragma unroll
    for (int fm = 0; fm < 4; ++fm)
      #pragma unroll
      for (int fn = 0; fn < 4; ++fn)
        acc[fm][fn] = mfma16(a[fm], bb[fn], acc[fm][fn]);
  }

  #pragma unroll
  for (int fm = 0; fm < 4; ++fm)
    #pragma unroll
    for (int r = 0; r < 4; ++r){
      int i = fm*16 + lg*4 + r;
      float s = 0.f, ss = 0.f;
      #pragma unroll
      for (int fn = 0; fn < 4; ++fn){
        int px = wid*64 + fn*16 + pc;
        float v = acc[fm][fn][r];
        out2[(b*64 + i)*HW + p0 + px] = v;
        s += v; ss += v*v;
      }
      s += __shfl_xor(s,1); s += __shfl_xor(s,2); s += __shfl_xor(s,4); s += __shfl_xor(s,8);
      ss += __shfl_xor(ss,1); ss += __shfl_xor(ss,2); ss += __shfl_xor(ss,4); ss += __shfl_xor(ss,8);
      if (pc == 0){ wp[(wid*64 + i)*2] = s; wp[(wid*64 + i)*2 + 1] = ss; }
    }
  __syncthreads();
  if (tid < 64){
    float s = 0.f, ss = 0.f;
    #pragma unroll
    for (int w = 0; w < 4; ++w){ s += wp[(w*64 + tid)*2]; ss += wp[(w*64 + tid)*2 + 1]; }
    int blin = b*64 + chunk;
    st2[(blin*64 + tid)*2] = s; st2[(blin*64 + tid)*2 + 1] = ss;
  }
}

// ---------------- k4c: out3T = relu(bn2(out2)) NHWC bf16, coalesced via LDS transpose ----------------
__global__ void k4c_out3(const float* __restrict__ out2, const float* __restrict__ bn2, bfu* out3T){
  __shared__ bfu lds[128*72];
  int b = blockIdx.y, h = blockIdx.x;        // grid (128,4)
  int t = threadIdx.x;
  int px = t & 127, ch = (t >> 7)*32;
  #pragma unroll 1
  for (int cc = 0; cc < 32; cc += 4){
    int c = ch + cc;
    float x0 = out2[((b*64 + c+0) << 14) + (h << 7) + px];
    float x1 = out2[((b*64 + c+1) << 14) + (h << 7) + px];
    float x2 = out2[((b*64 + c+2) << 14) + (h << 7) + px];
    float x3 = out2[((b*64 + c+3) << 14) + (h << 7) + px];
    x0 = bn2[(c+0)*2]*x0 + bn2[(c+0)*2+1]; x0 = x0 > 0.f ? x0 : 0.f;
    x1 = bn2[(c+1)*2]*x1 + bn2[(c+1)*2+1]; x1 = x1 > 0.f ? x1 : 0.f;
    x2 = bn2[(c+2)*2]*x2 + bn2[(c+2)*2+1]; x2 = x2 > 0.f ? x2 : 0.f;
    x3 = bn2[(c+3)*2]*x3 + bn2[(c+3)*2+1]; x3 = x3 > 0.f ? x3 : 0.f;
    ushort4 pk; pk.x = f2bf(x0); pk.y = f2bf(x1); pk.z = f2bf(x2); pk.w = f2bf(x3);
    *(ushort4*)&lds[px*72 + c] = pk;
  }
  __syncthreads();
  uint4* dst = (uint4*)out3T;
  #pragma unroll
  for (int k = 0; k < 4; ++k){
    int idx = k*256 + t;                     // 0..1023
    int pix = idx >> 3, sub = idx & 7;
    uint4 v = *(const uint4*)&lds[pix*72 + sub*8];
    dst[((size_t)(b*HP + h+1)*HP + (pix+1))*8 + sub] = v;
  }
}

// ---------------- k5: conv3 (implicit GEMM M=64,K=576), 512 blocks + BN3 stats ----------------
__global__ __launch_bounds__(256) void k5_conv3(
    const bfu* __restrict__ out3T, const bfu* __restrict__ A3,
    float* __restrict__ outc, float* __restrict__ st3){
  __shared__ bfu lds[180*72];                // 10x18 cells, 25,920 B
  __shared__ float wp[512];
  int tid = threadIdx.x;
  int b = blockIdx.y, tile = blockIdx.x;     // 0..127
  int h0 = (tile >> 3)*8, w0 = (tile & 7)*16;
  const uint4* src4 = (const uint4*)out3T;
  for (int s = tid; s < 180*8; s += 256){
    int cell = s >> 3, sub = s & 7;
    int th = cell/18, tw = cell - th*18;
    *(uint4*)&lds[cell*72 + sub*8] = src4[(((b*HP + h0+th)*HP) + (w0+tw))*8 + sub];
  }
  __syncthreads();

  int wid = tid >> 6, l = tid & 63, lg = l >> 4, pc = l & 15;
  f32x4 acc[4][2];
  #pragma unroll
  for (int i = 0; i < 4; ++i){ acc[i][0] = f32x4{0.f,0.f,0.f,0.f}; acc[i][1] = f32x4{0.f,0.f,0.f,0.f}; }
  const uint4* A4 = (const uint4*)A3;
  #pragma unroll 3
  for (int tap2 = 0; tap2 < 9; ++tap2){
    int kh = tap2/3, kw = tap2 - kh*3;
    #pragma unroll
    for (int jc = 0; jc < 2; ++jc){
      bf16x8 a[4], bb[2];
      #pragma unroll
      for (int fm = 0; fm < 4; ++fm)
        a[fm] = __builtin_bit_cast(bf16x8, A4[tap2*512 + (fm*16 + pc)*8 + jc*4 + lg]);
      #pragma unroll
      for (int fn = 0; fn < 2; ++fn){
        int cell = (wid*2 + fn + kh)*18 + (pc + kw);
        bb[fn] = ldsfrag(&lds[cell*72 + jc*32 + lg*8]);
      }
      #pragma unroll
      for (int fm = 0; fm < 4; ++fm)
        #pragma unroll
        for (int fn = 0; fn < 2; ++fn)
          acc[fm][fn] = mfma16(a[fm], bb[fn], acc[fm][fn]);
    }
  }
  #pragma unroll
  for (int fm = 0; fm < 4; ++fm)
    #pragma unroll
    for (int r = 0; r < 4; ++r){
      int c = fm*16 + lg*4 + r;
      float s = 0.f, ss = 0.f;
      #pragma unroll
      for (int fn = 0; fn < 2; ++fn){
        int pr = wid*2 + fn;
        float v = acc[fm][fn][r];
        outc[((b*64 + c)*128 + h0 + pr)*128 + (w0 + pc)] = v;
        s += v; ss += v*v;
      }
      s += __shfl_xor(s,1); s += __shfl_xor(s,2); s += __shfl_xor(s,4); s += __shfl_xor(s,8);
      ss += __shfl_xor(ss,1); ss += __shfl_xor(ss,2); ss += __shfl_xor(ss,4); ss += __shfl_xor(ss,8);
      if (pc == 0){ wp[(wid*64 + c)*2] = s; wp[(wid*64 + c)*2 + 1] = ss; }
    }
  __syncthreads();
  if (tid < 64){
    float s = 0.f, ss = 0.f;
    #pragma unroll
    for (int w = 0; w < 4; ++w){ s += wp[(w*64 + tid)*2]; ss += wp[(w*64 + tid)*2 + 1]; }
    int blin = b*128 + tile;
    st3[(blin*64 + tid)*2] = s; st3[(blin*64 + tid)*2 + 1] = ss;
  }
}

// ---------------- k6: final relu(bn3(conv3_pre)) in place, float4 ----------------
__global__ void k6_final(float4* __restrict__ out, const float* __restrict__ bn3){
  const int total4 = 4*64*HW/4;              // 1,048,576
  for (int i = blockIdx.x*256 + threadIdx.x; i < total4; i += gridDim.x*256){
    int c = (i >> 12) & 63;
    float a = bn3[c*2], be = bn3[c*2 + 1];
    float4 x = out[i];
    x.x = a*x.x + be; x.x = x.x > 0.f ? x.x : 0.f;
    x.y = a*x.y + be; x.y = x.y > 0.f ? x.y : 0.f;
    x.z = a*x.z + be; x.z = x.z > 0.f ? x.z : 0.f;
    x.w = a*x.w + be; x.w = x.w > 0.f ? x.w : 0.f;
    out[i] = x;
  }
}

extern "C" void kernel_launch(void* const* d_in, const int* in_sizes, int n_in,
                              void* d_out, int out_size, void* d_ws, size_t ws_size,
                              hipStream_t stream){
  const float* inp  = (const float*)d_in[0];
  const float* wgt  = (const float*)d_in[1];
  const float* w11w = (const float*)d_in[2];
  const float* b11  = (const float*)d_in[3];
  const float* w12w = (const float*)d_in[4];
  const float* b12  = (const float*)d_in[5];
  const float* w21w = (const float*)d_in[6];
  const float* b21  = (const float*)d_in[7];
  const float* W22  = (const float*)d_in[8];
  const float* b22  = (const float*)d_in[9];
  const float* lg   = (const float*)d_in[10];
  const float* lb   = (const float*)d_in[11];
  const float* brg  = (const float*)d_in[12];
  const float* brb  = (const float*)d_in[13];
  const float* w3w  = (const float*)d_in[14];
  const float* c3g  = (const float*)d_in[15];
  const float* c3b  = (const float*)d_in[16];

  if (ws_size < 53200000) return;

  char* ws = (char*)d_ws;
  bfu*   catT  = (bfu*)(ws);                     // 17,305,600
  bfu*   w11T  = (bfu*)(ws + 17305600);          //  8,652,800
  bfu*   out3T = (bfu*)(ws + 25958400);          //  8,652,800
  bfu*   A11   = (bfu*)(ws + 34611200);          //    294,912
  bfu*   A12   = (bfu*)(ws + 34906112);          //    663,552
  bfu*   A3    = (bfu*)(ws + 35569664);          //     73,728
  float* out1  = (float*)(ws + 35643392);        // 16,777,216
  float* poolP = (float*)(ws + 52420608);        //    131,072
  float* pooled= (float*)(ws + 52551680);        //      1,024
  bfu*   w22bf = (bfu*)(ws + 52552704);          //     32,768
  float* st13  = (float*)(ws + 52585472);        //    262,144 (st1 then st3 — disjoint in time)
  float* bn1   = (float*)(ws + 52847616);        //        512
  float* st2   = (float*)(ws + 52848128);        //    131,072
  float* bn2   = (float*)(ws + 52979200);        //        512
  float* bn3   = (float*)(ws + 52979712);        //        512
  float* outF  = (float*)d_out;

  k_zero_border<<<dim3(9),  dim3(256), 0, stream>>>(catT, w11T, out3T);
  k_prep_w  <<<dim3(512),  dim3(256), 0, stream>>>(w11w, w21w, w12w, w3w, A11, A12, A3);
  k_prep_cat<<<dim3(128,4),dim3(256), 0, stream>>>(inp, wgt, catT);
  k1_conv   <<<dim3(128,4),dim3(256), 0, stream>>>(catT, A11, b11, b21, w11T, poolP);
  k2a_pool  <<<dim3(1),    dim3(256), 0, stream>>>(poolP, pooled);
  k2b_w22   <<<dim3(64),   dim3(256), 0, stream>>>(pooled, W22, b22, w22bf);
  k3_fused  <<<dim3(64,4), dim3(256), 0, stream>>>(w11T, catT, A12, b12, out1, st13);
  k_bnstat  <<<dim3(1),    dim3(256), 0, stream>>>(st13, 256, 65536.f, lg, lb, bn1);
  k4_einsum <<<dim3(64,4), dim3(256), 0, stream>>>(out1, w22bf, bn1, outF, st2);
  k_bnstat  <<<dim3(1),    dim3(256), 0, stream>>>(st2, 256, 65536.f, brg, brb, bn2);
  k4c_out3  <<<dim3(128,4),dim3(256), 0, stream>>>(outF, bn2, out3T);
  k5_conv3  <<<dim3(128,4),dim3(256), 0, stream>>>(out3T, A3, outF, st13);
  k_bnstat  <<<dim3(1),    dim3(256), 0, stream>>>(st13, 512, 65536.f, c3g, c3b, bn3);
  k6_final  <<<dim3(1024), dim3(256), 0, stream>>>((float4*)outF, bn3);
}